// Round 6
// baseline (196.149 us; speedup 1.0000x reference)
//
#include <hip/hip_runtime.h>

typedef _Float16 f16x8 __attribute__((ext_vector_type(8)));
typedef float f32x4 __attribute__((ext_vector_type(4)));
typedef unsigned int u32x4 __attribute__((ext_vector_type(4)));

#define D_DIM 256
#define K_CL  128
#define BM    64
#define KPAD  132          // key row stride (u32)
#define MARGIN 0.1f

__device__ __forceinline__ unsigned pkf16(float a, float b) {
  return __builtin_bit_cast(unsigned, __builtin_amdgcn_cvt_pkrtz(a, b));
}

// 8 waves/block, 64 rows/tile, 128 clusters, grid-stride over tiles.
// fp16 MFMA path; zsq from z*z^T MFMA diagonal (per-row-const error, cancels
// in ranking/gap); csq numpy-pairwise-exact (8-lane tree == np 8-accumulator
// pattern, bit-identical); keys = (sq&~0x7F)|col in LDS overlay; reader pass
// finds two-smallest + writes s directly. Ambiguous rows (gap < MARGIN)
// re-resolved with the numpy-fp32-emulating pipeline (verified round 3),
// now parallelized (4 thr/cluster fp64 dot, parallel div+argmax).
extern "C" __global__ void __launch_bounds__(512, 8)
k_main(const float* __restrict__ z, const float* __restrict__ cen,
       float* __restrict__ s_out, float* __restrict__ c_out, int ntiles)
{
  __shared__ __align__(16) unsigned char pool[BM * KPAD * 4];  // z16 / keys / refine
  __shared__ float zsq[BM];
  __shared__ float csqnp[K_CL];
  __shared__ unsigned int amb_n;
  __shared__ unsigned char amb_rows[BM];
  __shared__ float zsq_np_sh, sum_sh;
  __shared__ unsigned long long wkey[2];

  const int tid = threadIdx.x;
  const int w   = tid >> 6;
  const int l   = tid & 63;
  const int l15 = l & 15;
  const int g   = l >> 4;

  // ---- csqnp: numpy-exact pairwise sumsq, 8 lanes per cluster, 2 passes.
  {
#pragma clang fp contract(off)
    const int sub = tid & 7;
#pragma unroll
    for (int p = 0; p < 2; ++p) {
      const int c = (tid >> 3) + (p << 6);
      const float* a = cen + (size_t)c * D_DIM;
      float blk[2];
#pragma unroll
      for (int b2 = 0; b2 < 2; ++b2) {
        const float* ab = a + (b2 << 7);
        float x = ab[sub];
        float r = x * x;
        for (int i = 1; i < 16; ++i) { x = ab[(i << 3) + sub]; r = r + x * x; }
        r = r + __shfl_xor(r, 1);   // ((r0+r1)+(r2+r3))+((r4+r5)+(r6+r7))
        r = r + __shfl_xor(r, 2);
        r = r + __shfl_xor(r, 4);
        blk[b2] = r;
      }
      if (sub == 0) csqnp[c] = blk[0] + blk[1];
    }
  }

  // ---- B fragments fp16 in regs: wave w owns clusters w*16..+15.
  // mfma_f32_16x16x32_f16 B layout: lane holds B[k=(l>>4)*8+i][n=l&15].
  f16x8 bf[8];
  {
    const int c = (w << 4) + l15;
    const float* crow = cen + (size_t)c * D_DIM;
#pragma unroll
    for (int k = 0; k < 8; ++k) {
      const int d0 = k * 32 + g * 8;
      const float4 v0 = *(const float4*)(crow + d0);
      const float4 v1 = *(const float4*)(crow + d0 + 4);
      bf[k] = __builtin_bit_cast(f16x8, (u32x4){pkf16(v0.x,v0.y), pkf16(v0.z,v0.w),
                                                pkf16(v1.x,v1.y), pkf16(v1.z,v1.w)});
    }
  }

  for (int tile = blockIdx.x; tile < ntiles; tile += gridDim.x) {
    const int row0 = tile * BM;
    if (tid == 0) amb_n = 0;

    // ---- stage z fp16 (XOR-swizzled 16B chunks), no reductions.
#pragma unroll
    for (int i = 0; i < 8; ++i) {
      const int r = (w << 3) + i;
      const float4 v = *(const float4*)(z + (size_t)(row0 + r) * D_DIM + (l << 2));
      const int boff = (r << 9) + ((((l >> 1) ^ (r & 31)) << 4) | ((l & 1) << 3));
      *(uint2*)(pool + boff) = make_uint2(pkf16(v.x, v.y), pkf16(v.z, v.w));
    }
    __syncthreads();                                        // bar1

    // ---- MFMA; waves 0..3 also accumulate z*z^T for row-tile rt==w.
    f32x4 acc[4];
    f32x4 zz = (f32x4){0.f, 0.f, 0.f, 0.f};
#pragma unroll
    for (int rt = 0; rt < 4; ++rt) acc[rt] = (f32x4){0.f, 0.f, 0.f, 0.f};
#pragma unroll
    for (int k = 0; k < 8; ++k) {
#pragma unroll
      for (int rt = 0; rt < 4; ++rt) {
        const int r = (rt << 4) + l15;   // A: lane holds A[m=l&15][k=(l>>4)*8+i]
        const int boff = (r << 9) + ((((k << 2) + g) ^ (r & 31)) << 4);
        const f16x8 af = *(const f16x8*)(pool + boff);
        acc[rt] = __builtin_amdgcn_mfma_f32_16x16x32_f16(af, bf[k], acc[rt], 0, 0, 0);
        if (rt == w)   // wave-uniform; only waves 0..3 match
          zz = __builtin_amdgcn_mfma_f32_16x16x32_f16(af, af, zz, 0, 0, 0);
      }
    }
    if (w < 4) {       // diag of C: row==col -> l15 == 4g+j, value in reg j
#pragma unroll
      for (int j = 0; j < 4; ++j)
        if (l15 == ((g << 2) + j)) zsq[(w << 4) + l15] = zz[j];
    }
    __syncthreads();                                        // bar2

    // ---- keys. C/D layout: row=(l>>4)*4+reg, col=l&15.
    unsigned* keybuf = (unsigned*)pool;
    const int col = (w << 4) + l15;
    const float cq = csqnp[col];
#pragma unroll
    for (int rt = 0; rt < 4; ++rt) {
#pragma unroll
      for (int j = 0; j < 4; ++j) {
        const int r = (rt << 4) + (g << 2) + j;
        const float sq = fmaxf(fmaf(-2.0f, acc[rt][j], zsq[r] + cq), 0.0f);
        keybuf[r * KPAD + col] = (__float_as_uint(sq) & 0xFFFFFF80u) | (unsigned)col;
      }
    }
    __syncthreads();                                        // bar3

    // ---- reader: 8 threads/row; two-smallest + rowsum + write s + c_out.
    {
      const int rr = tid >> 3;
      const unsigned* kp = keybuf + rr * KPAD + ((tid & 7) << 4);
      unsigned m1 = 0xFFFFFFFFu, m2 = 0xFFFFFFFFu;
      float t[16];
      float sum = 0.f;
#pragma unroll
      for (int q = 0; q < 4; ++q) {
        const u32x4 kv = *(const u32x4*)(kp + (q << 2));
#pragma unroll
        for (int e = 0; e < 4; ++e) {
          const unsigned u = kv[e];
          const unsigned mn = min(m1, u), mx = max(m1, u);
          m1 = mn; m2 = min(m2, mx);
          const float tv = __builtin_amdgcn_rcpf(
              1.0f + __builtin_amdgcn_sqrtf(__uint_as_float(u & 0xFFFFFF80u)));
          t[(q << 2) + e] = tv;
          sum += tv;
        }
      }
#pragma unroll
      for (int m = 1; m <= 4; m <<= 1) {
        const unsigned o1 = __shfl_xor(m1, m);
        const unsigned o2 = __shfl_xor(m2, m);
        sum += __shfl_xor(sum, m);
        const unsigned mn = min(m1, o1), mx = max(m1, o1);
        m1 = mn; m2 = min(mx, min(m2, o2));
      }
      const float rinv = __builtin_amdgcn_rcpf(sum);
      float* srow = s_out + (size_t)(row0 + rr) * K_CL + ((tid & 7) << 4);
#pragma unroll
      for (int q = 0; q < 4; ++q) {
        float4 sv;
        sv.x = t[(q << 2) + 0] * rinv; sv.y = t[(q << 2) + 1] * rinv;
        sv.z = t[(q << 2) + 2] * rinv; sv.w = t[(q << 2) + 3] * rinv;
        *(float4*)(srow + (q << 2)) = sv;
      }
      if ((tid & 7) == 0) {
        c_out[row0 + rr] = (float)(m1 & 0x7Fu);
        const float d1 = __uint_as_float(m1 & 0xFFFFFF80u);
        const float d2 = __uint_as_float(m2 & 0xFFFFFF80u);
        if ((d2 - d1) < MARGIN) {
          const unsigned idx = atomicAdd(&amb_n, 1u);
          amb_rows[idx] = (unsigned char)rr;
        }
      }
    }
    __syncthreads();                                        // bar4

    // ---- numpy-fp32-emulating refinement (parallelized), rare.
    unsigned na = amb_n;
    if (na > BM) na = BM;
    if (na) {
      float* zrow = (float*)pool;           // 256 f (overlays keys)
      float* stmp = (float*)pool + 256;     // 128 f
      for (unsigned e = 0; e < na; ++e) {
        const int r = amb_rows[e];
        __syncthreads();   // previous pool reads complete
        if (tid < 64)
          *(float4*)(zrow + (tid << 2)) =
              *(const float4*)(z + (size_t)(row0 + r) * D_DIM + (tid << 2));
        __syncthreads();
        if (tid < 8) {     // numpy-exact zsq of this row
#pragma clang fp contract(off)
          const int sub = tid;
          float blk[2];
#pragma unroll
          for (int b2 = 0; b2 < 2; ++b2) {
            const float* ab = zrow + (b2 << 7);
            float x = ab[sub];
            float rr2 = x * x;
            for (int i = 1; i < 16; ++i) { x = ab[(i << 3) + sub]; rr2 = rr2 + x * x; }
            rr2 = rr2 + __shfl_xor(rr2, 1);
            rr2 = rr2 + __shfl_xor(rr2, 2);
            rr2 = rr2 + __shfl_xor(rr2, 4);
            blk[b2] = rr2;
          }
          if (sub == 0) zsq_np_sh = blk[0] + blk[1];
        }
        // fp64 dot: 4 threads per cluster (reassociation ~1e-13, far below
        // the 1.7e-4 fp32 s_tmp tie quantum).
        const int c = tid >> 2, part = tid & 3;
        double d = 0.0;
        {
          const float* cp = cen + (size_t)c * D_DIM + (part << 6);
          const float* zp = zrow + (part << 6);
          for (int i = 0; i < 64; ++i)
            d += (double)zp[i] * (double)cp[i];
          d += __shfl_xor(d, 1);
          d += __shfl_xor(d, 2);
        }
        __syncthreads();   // zsq_np_sh visible; zrow reads done
        if (part == 0) {
#pragma clang fp contract(off)
          const float dotf = (float)d;                       // ~sgemm, CR
          const float sq   = (zsq_np_sh + csqnp[c]) - 2.0f * dotf;
          stmp[c] = 1.0f / (1.0f + sqrtf(fmaxf(sq, 0.0f)));  // np pow -1 path
        }
        __syncthreads();
        if (tid < 8) {     // numpy-exact sum of stmp[128]
#pragma clang fp contract(off)
          const int sub = tid;
          float rr2 = stmp[sub];
          for (int i = 1; i < 16; ++i) rr2 = rr2 + stmp[(i << 3) + sub];
          rr2 = rr2 + __shfl_xor(rr2, 1);
          rr2 = rr2 + __shfl_xor(rr2, 2);
          rr2 = rr2 + __shfl_xor(rr2, 4);
          if (sub == 0) sum_sh = rr2;
        }
        __syncthreads();
        if (tid < 128) {   // parallel divide + first-index-wins argmax
          const float s = stmp[tid] / sum_sh;                // IEEE div, like np
          unsigned long long key =
              ((unsigned long long)(0x7FFFFFFFu - __float_as_uint(s)) << 32) |
              (unsigned)tid;
#pragma unroll
          for (int m = 1; m < 64; m <<= 1) {
            const unsigned long long o = __shfl_xor(key, m);
            key = o < key ? o : key;
          }
          if ((tid & 63) == 0) wkey[tid >> 6] = key;
        }
        __syncthreads();
        if (tid == 0) {
          const unsigned long long k2 = wkey[0] < wkey[1] ? wkey[0] : wkey[1];
          c_out[row0 + r] = (float)(unsigned)(k2 & 0x7Fu);
        }
      }
    }
  }
}

extern "C" void kernel_launch(void* const* d_in, const int* in_sizes, int n_in,
                              void* d_out, int out_size, void* d_ws, size_t ws_size,
                              hipStream_t stream) {
  const float* z   = (const float*)d_in[0];
  const float* cen = (const float*)d_in[1];
  const int M = in_sizes[0] / D_DIM;   // 131072
  float* s_out = (float*)d_out;
  float* c_out = s_out + (size_t)M * K_CL;
  const int ntiles = M / BM;           // 2048
  const int nblk = ntiles < 1024 ? ntiles : 1024;   // 4 blocks/CU, grid-stride x2

  hipLaunchKernelGGL(k_main, dim3(nblk), dim3(512), 0, stream,
                     z, cen, s_out, c_out, ntiles);
}

// Round 7
// 122.255 us; speedup vs baseline: 1.6044x; 1.6044x over previous
//
#include <hip/hip_runtime.h>

typedef _Float16 f16x8 __attribute__((ext_vector_type(8)));
typedef float f32x4 __attribute__((ext_vector_type(4)));
typedef unsigned int u32x4 __attribute__((ext_vector_type(4)));

#define D_DIM 256
#define K_CL  128
#define BM    64
#define KPAD  132          // key row stride (u32)
#define MARGIN 0.1f

__device__ __forceinline__ unsigned pkf16(float a, float b) {
  return __builtin_bit_cast(unsigned, __builtin_amdgcn_cvt_pkrtz(a, b));
}

// 8 waves/block, 64 rows/tile, 128 clusters, grid-stride over tiles.
// fp16 MFMA path; zsq from z*z^T MFMA diagonal (per-row-const error, cancels
// in ranking/gap); csq numpy-pairwise-exact; keys = (sq&~0x7F)|col in LDS
// overlay; reader pass finds two-smallest + writes s directly. Ambiguous rows
// (gap < MARGIN) re-resolved with the numpy-fp32-emulating pipeline (verified
// round 3), parallelized. NOTE: no min-occupancy in launch_bounds — round 6's
// (512,8) forced VGPR=32 and spilled ~136MB/dispatch to scratch.
extern "C" __global__ void __launch_bounds__(512)
k_main(const float* __restrict__ z, const float* __restrict__ cen,
       float* __restrict__ s_out, float* __restrict__ c_out, int ntiles)
{
  __shared__ __align__(16) unsigned char pool[BM * KPAD * 4];  // z16 / keys / refine
  __shared__ float zsq[BM];
  __shared__ float csqnp[K_CL];
  __shared__ unsigned int amb_n;
  __shared__ unsigned char amb_rows[BM];
  __shared__ float zsq_np_sh, sum_sh;
  __shared__ unsigned long long wkey[2];

  const int tid = threadIdx.x;
  const int w   = tid >> 6;
  const int l   = tid & 63;
  const int l15 = l & 15;
  const int g   = l >> 4;

  // ---- csqnp: numpy-exact pairwise sumsq, 8 lanes per cluster, 2 passes.
  {
#pragma clang fp contract(off)
    const int sub = tid & 7;
#pragma unroll
    for (int p = 0; p < 2; ++p) {
      const int c = (tid >> 3) + (p << 6);
      const float* a = cen + (size_t)c * D_DIM;
      float blk[2];
#pragma unroll
      for (int b2 = 0; b2 < 2; ++b2) {
        const float* ab = a + (b2 << 7);
        float x = ab[sub];
        float r = x * x;
        for (int i = 1; i < 16; ++i) { x = ab[(i << 3) + sub]; r = r + x * x; }
        r = r + __shfl_xor(r, 1);   // ((r0+r1)+(r2+r3))+((r4+r5)+(r6+r7))
        r = r + __shfl_xor(r, 2);
        r = r + __shfl_xor(r, 4);
        blk[b2] = r;
      }
      if (sub == 0) csqnp[c] = blk[0] + blk[1];
    }
  }

  // ---- B fragments fp16 in regs: wave w owns clusters w*16..+15.
  // mfma_f32_16x16x32_f16 B layout: lane holds B[k=(l>>4)*8+i][n=l&15].
  f16x8 bf[8];
  {
    const int c = (w << 4) + l15;
    const float* crow = cen + (size_t)c * D_DIM;
#pragma unroll
    for (int k = 0; k < 8; ++k) {
      const int d0 = k * 32 + g * 8;
      const float4 v0 = *(const float4*)(crow + d0);
      const float4 v1 = *(const float4*)(crow + d0 + 4);
      bf[k] = __builtin_bit_cast(f16x8, (u32x4){pkf16(v0.x,v0.y), pkf16(v0.z,v0.w),
                                                pkf16(v1.x,v1.y), pkf16(v1.z,v1.w)});
    }
  }

  for (int tile = blockIdx.x; tile < ntiles; tile += gridDim.x) {
    const int row0 = tile * BM;
    if (tid == 0) amb_n = 0;

    // ---- stage z fp16 (XOR-swizzled 16B chunks), no reductions.
#pragma unroll
    for (int i = 0; i < 8; ++i) {
      const int r = (w << 3) + i;
      const float4 v = *(const float4*)(z + (size_t)(row0 + r) * D_DIM + (l << 2));
      const int boff = (r << 9) + ((((l >> 1) ^ (r & 31)) << 4) | ((l & 1) << 3));
      *(uint2*)(pool + boff) = make_uint2(pkf16(v.x, v.y), pkf16(v.z, v.w));
    }
    __syncthreads();                                        // bar1

    // ---- MFMA; waves 0..3 also accumulate z*z^T for row-tile rt==w.
    f32x4 acc[4];
    f32x4 zz = (f32x4){0.f, 0.f, 0.f, 0.f};
#pragma unroll
    for (int rt = 0; rt < 4; ++rt) acc[rt] = (f32x4){0.f, 0.f, 0.f, 0.f};
#pragma unroll
    for (int k = 0; k < 8; ++k) {
#pragma unroll
      for (int rt = 0; rt < 4; ++rt) {
        const int r = (rt << 4) + l15;   // A: lane holds A[m=l&15][k=(l>>4)*8+i]
        const int boff = (r << 9) + ((((k << 2) + g) ^ (r & 31)) << 4);
        const f16x8 af = *(const f16x8*)(pool + boff);
        acc[rt] = __builtin_amdgcn_mfma_f32_16x16x32_f16(af, bf[k], acc[rt], 0, 0, 0);
        if (rt == w)   // wave-uniform; only waves 0..3 match
          zz = __builtin_amdgcn_mfma_f32_16x16x32_f16(af, af, zz, 0, 0, 0);
      }
    }
    if (w < 4) {       // diag of C: row==col -> l15 == 4g+j, value in reg j
#pragma unroll
      for (int j = 0; j < 4; ++j)
        if (l15 == ((g << 2) + j)) zsq[(w << 4) + l15] = zz[j];
    }
    __syncthreads();                                        // bar2

    // ---- keys. C/D layout: row=(l>>4)*4+reg, col=l&15.
    unsigned* keybuf = (unsigned*)pool;
    const int col = (w << 4) + l15;
    const float cq = csqnp[col];
#pragma unroll
    for (int rt = 0; rt < 4; ++rt) {
#pragma unroll
      for (int j = 0; j < 4; ++j) {
        const int r = (rt << 4) + (g << 2) + j;
        const float sq = fmaxf(fmaf(-2.0f, acc[rt][j], zsq[r] + cq), 0.0f);
        keybuf[r * KPAD + col] = (__float_as_uint(sq) & 0xFFFFFF80u) | (unsigned)col;
      }
    }
    __syncthreads();                                        // bar3

    // ---- reader: 8 threads/row; two-smallest + rowsum + write s + c_out.
    {
      const int rr = tid >> 3;
      const unsigned* kp = keybuf + rr * KPAD + ((tid & 7) << 4);
      unsigned m1 = 0xFFFFFFFFu, m2 = 0xFFFFFFFFu;
      float t[16];
      float sum = 0.f;
#pragma unroll
      for (int q = 0; q < 4; ++q) {
        const u32x4 kv = *(const u32x4*)(kp + (q << 2));
#pragma unroll
        for (int e = 0; e < 4; ++e) {
          const unsigned u = kv[e];
          const unsigned mn = min(m1, u), mx = max(m1, u);
          m1 = mn; m2 = min(m2, mx);
          const float tv = __builtin_amdgcn_rcpf(
              1.0f + __builtin_amdgcn_sqrtf(__uint_as_float(u & 0xFFFFFF80u)));
          t[(q << 2) + e] = tv;
          sum += tv;
        }
      }
#pragma unroll
      for (int m = 1; m <= 4; m <<= 1) {
        const unsigned o1 = __shfl_xor(m1, m);
        const unsigned o2 = __shfl_xor(m2, m);
        sum += __shfl_xor(sum, m);
        const unsigned mn = min(m1, o1), mx = max(m1, o1);
        m1 = mn; m2 = min(mx, min(m2, o2));
      }
      const float rinv = __builtin_amdgcn_rcpf(sum);
      float* srow = s_out + (size_t)(row0 + rr) * K_CL + ((tid & 7) << 4);
#pragma unroll
      for (int q = 0; q < 4; ++q) {
        float4 sv;
        sv.x = t[(q << 2) + 0] * rinv; sv.y = t[(q << 2) + 1] * rinv;
        sv.z = t[(q << 2) + 2] * rinv; sv.w = t[(q << 2) + 3] * rinv;
        *(float4*)(srow + (q << 2)) = sv;
      }
      if ((tid & 7) == 0) {
        c_out[row0 + rr] = (float)(m1 & 0x7Fu);
        const float d1 = __uint_as_float(m1 & 0xFFFFFF80u);
        const float d2 = __uint_as_float(m2 & 0xFFFFFF80u);
        if ((d2 - d1) < MARGIN) {
          const unsigned idx = atomicAdd(&amb_n, 1u);
          amb_rows[idx] = (unsigned char)rr;
        }
      }
    }
    __syncthreads();                                        // bar4

    // ---- numpy-fp32-emulating refinement (parallelized), rare.
    unsigned na = amb_n;
    if (na > BM) na = BM;
    if (na) {
      float* zrow = (float*)pool;           // 256 f (overlays keys)
      float* stmp = (float*)pool + 256;     // 128 f
      for (unsigned e = 0; e < na; ++e) {
        const int r = amb_rows[e];
        __syncthreads();   // previous pool reads complete
        if (tid < 64)
          *(float4*)(zrow + (tid << 2)) =
              *(const float4*)(z + (size_t)(row0 + r) * D_DIM + (tid << 2));
        __syncthreads();
        if (tid < 8) {     // numpy-exact zsq of this row
#pragma clang fp contract(off)
          const int sub = tid;
          float blk[2];
#pragma unroll
          for (int b2 = 0; b2 < 2; ++b2) {
            const float* ab = zrow + (b2 << 7);
            float x = ab[sub];
            float rr2 = x * x;
            for (int i = 1; i < 16; ++i) { x = ab[(i << 3) + sub]; rr2 = rr2 + x * x; }
            rr2 = rr2 + __shfl_xor(rr2, 1);
            rr2 = rr2 + __shfl_xor(rr2, 2);
            rr2 = rr2 + __shfl_xor(rr2, 4);
            blk[b2] = rr2;
          }
          if (sub == 0) zsq_np_sh = blk[0] + blk[1];
        }
        // fp64 dot: 4 threads per cluster (reassociation ~1e-13, far below
        // the 1.7e-4 fp32 s_tmp tie quantum).
        const int c = tid >> 2, part = tid & 3;
        double d = 0.0;
        {
          const float* cp = cen + (size_t)c * D_DIM + (part << 6);
          const float* zp = zrow + (part << 6);
          for (int i = 0; i < 64; ++i)
            d += (double)zp[i] * (double)cp[i];
          d += __shfl_xor(d, 1);
          d += __shfl_xor(d, 2);
        }
        __syncthreads();   // zsq_np_sh visible; zrow reads done
        if (part == 0) {
#pragma clang fp contract(off)
          const float dotf = (float)d;                       // ~sgemm, CR
          const float sq   = (zsq_np_sh + csqnp[c]) - 2.0f * dotf;
          stmp[c] = 1.0f / (1.0f + sqrtf(fmaxf(sq, 0.0f)));  // np pow -1 path
        }
        __syncthreads();
        if (tid < 8) {     // numpy-exact sum of stmp[128]
#pragma clang fp contract(off)
          const int sub = tid;
          float rr2 = stmp[sub];
          for (int i = 1; i < 16; ++i) rr2 = rr2 + stmp[(i << 3) + sub];
          rr2 = rr2 + __shfl_xor(rr2, 1);
          rr2 = rr2 + __shfl_xor(rr2, 2);
          rr2 = rr2 + __shfl_xor(rr2, 4);
          if (sub == 0) sum_sh = rr2;
        }
        __syncthreads();
        if (tid < 128) {   // parallel divide + first-index-wins argmax
          const float s = stmp[tid] / sum_sh;                // IEEE div, like np
          unsigned long long key =
              ((unsigned long long)(0x7FFFFFFFu - __float_as_uint(s)) << 32) |
              (unsigned)tid;
#pragma unroll
          for (int m = 1; m < 64; m <<= 1) {
            const unsigned long long o = __shfl_xor(key, m);
            key = o < key ? o : key;
          }
          if ((tid & 63) == 0) wkey[tid >> 6] = key;
        }
        __syncthreads();
        if (tid == 0) {
          const unsigned long long k2 = wkey[0] < wkey[1] ? wkey[0] : wkey[1];
          c_out[row0 + r] = (float)(unsigned)(k2 & 0x7Fu);
        }
      }
    }
  }
}

extern "C" void kernel_launch(void* const* d_in, const int* in_sizes, int n_in,
                              void* d_out, int out_size, void* d_ws, size_t ws_size,
                              hipStream_t stream) {
  const float* z   = (const float*)d_in[0];
  const float* cen = (const float*)d_in[1];
  const int M = in_sizes[0] / D_DIM;   // 131072
  float* s_out = (float*)d_out;
  float* c_out = s_out + (size_t)M * K_CL;
  const int ntiles = M / BM;           // 2048
  const int nblk = ntiles < 1024 ? ntiles : 1024;   // 4 blocks/CU, grid-stride x2

  hipLaunchKernelGGL(k_main, dim3(nblk), dim3(512), 0, stream,
                     z, cen, s_out, c_out, ntiles);
}